// Round 1
// baseline (522.129 us; speedup 1.0000x reference)
//
#include <hip/hip_runtime.h>
#include <math.h>

#define NV 128         // vector length (complex) = 8*8*2
#define NTRI 8256      // lower-tri entries of 128x128
#define NPAD8 8704     // triangle with each row padded to a multiple of 8 complex
#define KAP 0.276f
#define MAXIT 20
#define TPB 512        // 8 waves; LDS ~79 KB -> 2 blocks/CU

__device__ __forceinline__ float2 f2(float x, float y){ return make_float2(x, y); }
__device__ __forceinline__ float2 cadd(float2 a, float2 b){ return make_float2(a.x+b.x, a.y+b.y); }
__device__ __forceinline__ float2 csub(float2 a, float2 b){ return make_float2(a.x-b.x, a.y-b.y); }
__device__ __forceinline__ float2 cmul(float2 a, float2 b){ return make_float2(a.x*b.x - a.y*b.y, a.x*b.y + a.y*b.x); }
__device__ __forceinline__ float2 cmulc(float2 a, float2 b){ // conj(a)*b
  return make_float2(a.x*b.x + a.y*b.y, a.x*b.y - a.y*b.x); }
__device__ __forceinline__ float2 cmac(float2 acc, float2 a, float2 b){ // acc += a*b
  acc.x = fmaf(a.x, b.x, fmaf(-a.y, b.y, acc.x));
  acc.y = fmaf(a.x, b.y, fmaf( a.y, b.x, acc.y));
  return acc; }
__device__ __forceinline__ float2 cmacc(float2 acc, float2 a, float2 b){ // acc += conj(a)*b
  acc.x = fmaf(a.x, b.x, fmaf( a.y, b.y, acc.x));
  acc.y = fmaf(a.x, b.y, fmaf(-a.y, b.x, acc.y));
  return acc; }
__device__ __forceinline__ float2 cdiv(float2 n, float2 d){
  float s = 1.0f / fmaf(d.x, d.x, d.y*d.y);
  return make_float2((n.x*d.x + n.y*d.y)*s, (n.y*d.x - n.x*d.y)*s); }

// row r start in the 8-padded triangle: r = 8a+b -> 8*(a+1)*(4a+b). Always 8-aligned.
__device__ __forceinline__ int rowoff8(int r){
  const int a = r >> 3;
  return ((a + 1) * ((a << 2) + (r & 7))) << 3;
}

// sum over the 8 lanes {c=0..3} x {h=0,1} of a pair group (xor 1,2,32)
__device__ __forceinline__ float2 red8(float2 v){
  v.x += __shfl_xor(v.x, 1);  v.y += __shfl_xor(v.y, 1);
  v.x += __shfl_xor(v.x, 2);  v.y += __shfl_xor(v.y, 2);
  v.x += __shfl_xor(v.x, 32); v.y += __shfl_xor(v.y, 32);
  return v;
}

// Wilson-Dirac hop. EF = coefficient sign of G on the FORWARD hop:
//   D : fwd (I - G), bwd (I + G) -> EF=-1 ; Ddag : EF=+1
template<int EF>
__device__ __forceinline__ void dirac(const float2* __restrict__ U,
                                      const float2* __restrict__ vin,
                                      float2* __restrict__ vout, int t)
{
  if (t < NV) {
    const int s = t & 1, site = t >> 1;
    const int yi = site & 7, xi = site >> 3;
    const int xp = (xi+1)&7, xm = (xi-1)&7, yp = (yi+1)&7, ym = (yi-1)&7;
    float2 acc;
    {
      const int bf = (xp<<4) + (yi<<1);
      float2 fs = vin[bf + s], fo = vin[bf + (s^1)];
      float2 cf = (EF > 0) ? cadd(fs, fo) : csub(fs, fo);
      acc = cmul(U[(xi<<3)+yi], cf);
      const int bb = (xm<<4) + (yi<<1);
      float2 bs = vin[bb + s], bo = vin[bb + (s^1)];
      float2 cb = (EF > 0) ? csub(bs, bo) : cadd(bs, bo);
      acc = cadd(acc, cmulc(U[(xm<<3)+yi], cb));
    }
    {
      const float tg = s ? 1.0f : -1.0f;
      const float gf = (float)EF * tg;
      const int bf = (xi<<4) + (yp<<1);
      float2 fs = vin[bf + s], fo = vin[bf + (s^1)];
      float2 cf = make_float2(fmaf(-gf, fo.y, fs.x), fmaf(gf, fo.x, fs.y));
      acc = cadd(acc, cmul(U[64 + (xi<<3)+yi], cf));
      const float gb = -gf;
      const int bb = (xi<<4) + (ym<<1);
      float2 bs = vin[bb + s], bo = vin[bb + (s^1)];
      float2 cb = make_float2(fmaf(-gb, bo.y, bs.x), fmaf(gb, bo.x, bs.y));
      acc = cadd(acc, cmulc(U[64 + (xi<<3)+ym], cb));
    }
    float2 v0 = vin[t];
    vout[t] = make_float2(fmaf(-KAP, acc.x, v0.x), fmaf(-KAP, acc.y, v0.y));
  }
  __syncthreads();
}

// z = L^H (L v), L in 8-padded zero-filled LDS triangle.
//
// Pair-balanced schedule: each 4-lane group (wave w, sub-pair q, half h)
// owns the row/column pair (rlo = 8w+q, rhi = 127-rlo). Pair total = 17
// eight-wide slabs; group A (h=0) does 9, group B (h=1) does 8 -> every
// wave runs a UNIFORM, fully-unrolled 8-iter loop + a half-wave epilogue.
// All diagonal-crossing reads land in same-row zero pad, so no masking.
// Partials combine over the 8 lanes via shfl_xor(1,2,32).
__device__ __forceinline__ void precond(const float2* __restrict__ Lc2,
                                        const float2* __restrict__ vin,
                                        float2* __restrict__ wvv,
                                        float2* __restrict__ vout,
                                        int w, int lane)
{
  const int c  = lane & 3;
  const int g  = lane >> 2;
  const int q  = g & 7;
  const int h  = g >> 3;
  const int c2 = c << 1;
  const int rlo = (w << 3) + q;        // 0..63
  const int rhi = 127 - rlo;           // 64..127
  const int bLo = rowoff8(rlo);
  const int bHi = rowoff8(rhi);

  // ---- pass 1: w_r = sum_{j<=r} L[r][j] v[j] ----
  {
    float2 a0 = f2(0.f, 0.f), a1 = f2(0.f, 0.f);
    #pragma unroll
    for (int i = 0; i < 8; ++i) {
      if (i <= w) {
        // A: rlo slab i ; B: rhi slab 8-w+i
        const int k  = h ? (8 - w + i) : i;
        const int jo = (k << 3) + c2;
        const int base = h ? bHi : bLo;
        const float4 Lp = *(const float4*)&Lc2[base + jo];
        const float4 vp = *(const float4*)&vin[jo];
        a0 = cmac(cmac(a0, f2(Lp.x,Lp.y), f2(vp.x,vp.y)), f2(Lp.z,Lp.w), f2(vp.z,vp.w));
      } else {
        // A: rhi slab i-w-1 ; B: rhi slab 8-w+i
        const int k  = h ? (8 - w + i) : (i - w - 1);
        const int jo = (k << 3) + c2;
        const float4 Lp = *(const float4*)&Lc2[bHi + jo];
        const float4 vp = *(const float4*)&vin[jo];
        a1 = cmac(cmac(a1, f2(Lp.x,Lp.y), f2(vp.x,vp.y)), f2(Lp.z,Lp.w), f2(vp.z,vp.w));
      }
    }
    if (!h) {  // epilogue slab 9 of group A: rhi slab 7-w
      const int jo = ((7 - w) << 3) + c2;
      const float4 Lp = *(const float4*)&Lc2[bHi + jo];
      const float4 vp = *(const float4*)&vin[jo];
      a1 = cmac(cmac(a1, f2(Lp.x,Lp.y), f2(vp.x,vp.y)), f2(Lp.z,Lp.w), f2(vp.z,vp.w));
    }
    // h=0: a0 = full rlo, a1 = rhi part ; h=1: a0+a1 = rhi part
    float2 vLo = h ? f2(0.f, 0.f) : a0;
    float2 vHi = h ? cadd(a0, a1) : a1;
    vLo = red8(vLo);
    vHi = red8(vHi);
    if (c == 0) wvv[h ? rhi : rlo] = h ? vHi : vLo;
  }
  __syncthreads();

  // ---- pass 2: z_j = sum_{i>=j} conj(L[i][j]) w[i] ----
  {
    float2 a0 = f2(0.f, 0.f), a1 = f2(0.f, 0.f);
    #pragma unroll
    for (int i = 0; i < 8; ++i) {
      int k, j;
      if (i <= w) {
        // A: jhi slab 15-w+i ; B: jlo slab 8+i
        k = h ? (8 + i) : (15 - w + i);
        j = h ? rlo : rhi;
      } else {
        // A: jlo slab i-1 ; B: jlo slab 8+i
        k = h ? (8 + i) : (i - 1);
        j = rlo;
      }
      const int u    = (k + 1) << 3;                 // rowoff8(i0+1)-rowoff8(i0)
      const int off0 = u * ((k << 2) + c2) + j;      // rowoff8(8k+c2) + j
      const int i0   = (k << 3) + c2;
      const float2 La = Lc2[off0];
      const float2 Lb = Lc2[off0 + u];
      const float4 wp = *(const float4*)&wvv[i0];
      if (i <= w) a0 = cmacc(cmacc(a0, La, f2(wp.x,wp.y)), Lb, f2(wp.z,wp.w));
      else        a1 = cmacc(cmacc(a1, La, f2(wp.x,wp.y)), Lb, f2(wp.z,wp.w));
    }
    if (!h) {  // epilogue slab 9 of group A: jlo slab 7
      const int off0 = (28 + c2 << 6) / 8 * 8;       // placeholder avoided below
      (void)off0;
      const int u2   = 64;                           // 8*(7+1)
      const int o0   = u2 * (28 + c2) + rlo;         // rowoff8(56+c2) + jlo
      const float2 La = Lc2[o0];
      const float2 Lb = Lc2[o0 + u2];
      const float4 wp = *(const float4*)&wvv[56 + c2];
      a1 = cmacc(cmacc(a1, La, f2(wp.x,wp.y)), Lb, f2(wp.z,wp.w));
    }
    // h=0: a0 = full jhi, a1 = jlo part ; h=1: a0+a1 = jlo part
    float2 vJhi = h ? f2(0.f, 0.f) : a0;
    float2 vJlo = h ? cadd(a0, a1) : a1;
    vJhi = red8(vJhi);
    vJlo = red8(vJlo);
    if (c == 0) vout[h ? rlo : rhi] = h ? vJlo : vJhi;
  }
  __syncthreads();                                   // z visible to all consumers
}

// conj(a).c over t<128; scal slot double-buffered; internal barrier.
__device__ __forceinline__ float2 block_dot(const float2* __restrict__ a, const float2* __restrict__ c,
                            float2* __restrict__ scal, int t, int slot)
{
  if (t < NV) {
    float2 v = cmacc(f2(0.f,0.f), a[t], c[t]);
    #pragma unroll
    for (int off = 32; off > 0; off >>= 1) {
      v.x += __shfl_down(v.x, off, 64);
      v.y += __shfl_down(v.y, off, 64);
    }
    if ((t & 63) == 0) scal[(slot<<1) + (t >> 6)] = v;
  }
  __syncthreads();
  return cadd(scal[slot<<1], scal[(slot<<1)+1]);
}

extern "C" __global__ void __launch_bounds__(TPB, 4)
cg_loss_kernel(const float* __restrict__ nre, const float* __restrict__ nim,
               const float* __restrict__ theta, const float* __restrict__ bin,
               float* __restrict__ out, float invB)
{
  __shared__ __align__(16) float2 Lc2[NPAD8];       // 69632 B 8-padded triangle (pads zeroed)
  __shared__ __align__(16) float2 Uc[128];
  __shared__ __align__(16) float2 bv[NV], xv[NV], rv[NV], pv[NV];
  __shared__ __align__(16) float2 zv[NV], Apv[NV], tv[NV], wv[NV];
  __shared__ float2 scal[8];
  // total LDS = 69632 + 1024 + 8192 + 64 = 78912 B -> 2 blocks/CU

  const int t = threadIdx.x;
  const long long b = blockIdx.x;
  const int w = t >> 6, lane = t & 63;

  // ---- zero the padded triangle (pads must read as 0), init vectors ----
  #pragma unroll
  for (int p = t; p < NPAD8; p += TPB) Lc2[p] = make_float2(0.f, 0.f);
  if (t < NV) {
    float th = theta[b * 128 + t];
    float sn, cs;
    sincosf(th, &sn, &cs);
    Uc[t] = make_float2(cs, sn);                    // exp(i*theta)
    float bb = bin[b * 128 + t];
    bv[t] = make_float2(bb, 0.f);
    xv[t] = make_float2(0.f, 0.f);
    rv[t] = make_float2(bb, 0.f);                   // r = b - A(0)
  }
  __syncthreads();

  // ---- stage L into padded LDS; global reads fully coalesced (b32 strided) ----
  {
    const float* nreb = nre + b * NTRI;
    const float* nimb = nim + b * NTRI;
    for (int p = t; p < NTRI; p += TPB) {
      float re = nreb[p], im = nimb[p];
      int r = (int)((sqrtf(8.f * (float)p + 1.f) - 1.f) * 0.5f + 1e-3f);
      int tr = (r * (r + 1)) >> 1;
      if (tr > p)               { tr -= r; --r; }        // tri(r-1) = tri(r) - r
      else if (tr + r + 1 <= p) { tr += r + 1; ++r; }
      Lc2[rowoff8(r) + (p - tr)] = make_float2(re, im);
    }
  }
  __syncthreads();

  precond(Lc2, rv, wv, zv, w, lane);                // z = M r
  if (t < NV) pv[t] = zv[t];
  float2 rz = block_dot(rv, zv, scal, t, 0);        // internal barrier publishes pv

  #pragma unroll 1
  for (int it = 0; it < MAXIT; ++it) {
    dirac<-1>(Uc, pv, tv, t);                       // t1 = D p
    dirac<+1>(Uc, tv, Apv, t);                      // Ap = Ddag t1
    float2 pAp = block_dot(pv, Apv, scal, t, 1);
    if (t < NV) {
      float2 alpha = cdiv(rz, pAp);
      xv[t] = cmac(xv[t], alpha, pv[t]);            // x += alpha p
      rv[t] = csub(rv[t], cmul(alpha, Apv[t]));     // r -= alpha Ap
    }
    __syncthreads();                                // rv visible to pass 1
    precond(Lc2, rv, wv, zv, w, lane);              // z = M r
    float2 rz2 = block_dot(rv, zv, scal, t, 0);
    if (t < NV) {
      float2 beta = cdiv(rz2, rz);
      pv[t] = cmac(zv[t], beta, pv[t]);             // p = z + beta p
    }
    rz = rz2;
    __syncthreads();                                // pv visible to next dirac
  }

  // res = A x - b ; rn = ||res||
  dirac<-1>(Uc, xv, tv, t);
  dirac<+1>(Uc, tv, Apv, t);
  if (t < NV) {
    float2 d = csub(Apv[t], bv[t]);
    float v = fmaf(d.x, d.x, d.y * d.y);
    #pragma unroll
    for (int off = 32; off > 0; off >>= 1) v += __shfl_down(v, off, 64);
    if ((t & 63) == 0) scal[4 + (t >> 6)].x = v;
  }
  __syncthreads();
  if (t == 0) {
    float rn = sqrtf(scal[4].x + scal[5].x);
    atomicAdd(out, rn * invB);
  }
}

extern "C" void kernel_launch(void* const* d_in, const int* in_sizes, int n_in,
                              void* d_out, int out_size, void* d_ws, size_t ws_size,
                              hipStream_t stream)
{
  const float* nre   = (const float*)d_in[0];
  const float* nim   = (const float*)d_in[1];
  const float* theta = (const float*)d_in[2];
  const float* bin   = (const float*)d_in[3];
  float* out = (float*)d_out;
  const int B = in_sizes[0] / NTRI;   // 2048

  hipMemsetAsync(out, 0, sizeof(float), stream);
  cg_loss_kernel<<<B, TPB, 0, stream>>>(nre, nim, theta, bin, out, 1.0f / (float)B);
}

// Round 3
// 514.124 us; speedup vs baseline: 1.0156x; 1.0156x over previous
//
#include <hip/hip_runtime.h>
#include <math.h>

#define NV 128         // vector length (complex) = 8*8*2
#define NTRI 8256      // lower-tri entries of 128x128
#define NPAD8R 8960    // 8-padded triangle (8704) + 2-complex skew per row (256)
#define KAP 0.276f
#define MAXIT 20
#define TPB 512        // 8 waves; LDS ~81 KB -> 2 blocks/CU

__device__ __forceinline__ float2 f2(float x, float y){ return make_float2(x, y); }
__device__ __forceinline__ float2 cadd(float2 a, float2 b){ return make_float2(a.x+b.x, a.y+b.y); }
__device__ __forceinline__ float2 csub(float2 a, float2 b){ return make_float2(a.x-b.x, a.y-b.y); }
__device__ __forceinline__ float2 cmul(float2 a, float2 b){ return make_float2(a.x*b.x - a.y*b.y, a.x*b.y + a.y*b.x); }
__device__ __forceinline__ float2 cmulc(float2 a, float2 b){ // conj(a)*b
  return make_float2(a.x*b.x + a.y*b.y, a.x*b.y - a.y*b.x); }
__device__ __forceinline__ float2 cmac(float2 acc, float2 a, float2 b){ // acc += a*b
  acc.x = fmaf(a.x, b.x, fmaf(-a.y, b.y, acc.x));
  acc.y = fmaf(a.x, b.y, fmaf( a.y, b.x, acc.y));
  return acc; }
__device__ __forceinline__ float2 cmacc(float2 acc, float2 a, float2 b){ // acc += conj(a)*b
  acc.x = fmaf(a.x, b.x, fmaf( a.y, b.y, acc.x));
  acc.y = fmaf(a.x, b.y, fmaf(-a.y, b.x, acc.y));
  return acc; }
__device__ __forceinline__ float2 cdiv(float2 n, float2 d){
  float s = 1.0f / fmaf(d.x, d.x, d.y*d.y);
  return make_float2((n.x*d.x + n.y*d.y)*s, (n.y*d.x - n.x*d.y)*s); }

// Row r start: 8-padded triangle offset + 2-complex-per-row skew (bank spread).
// rowoff8(r) = 8*(a+1)*(4a+b), a=r>>3, b=r&7 ; soff8(r) = rowoff8(r) + 2r (even, 16B-aligned)
__device__ __forceinline__ int soff8(int r){
  const int a = r >> 3;
  return ((((a + 1) * ((a << 2) + (r & 7)))) << 3) + (r << 1);
}
// storage swizzle key for row r: XOR on complex-index bits 1-2 (granule bits 0-1)
__device__ __forceinline__ int skey(int r){ return ((r >> 1) & 3) << 1; }

// sum over the 8 lanes {c=0..3} x {h=0,1} of a pair group (xor 1,2,32)
__device__ __forceinline__ float2 red8(float2 v){
  v.x += __shfl_xor(v.x, 1);  v.y += __shfl_xor(v.y, 1);
  v.x += __shfl_xor(v.x, 2);  v.y += __shfl_xor(v.y, 2);
  v.x += __shfl_xor(v.x, 32); v.y += __shfl_xor(v.y, 32);
  return v;
}

// Wilson-Dirac hop. EF = coefficient sign of G on the FORWARD hop:
//   D : fwd (I - G), bwd (I + G) -> EF=-1 ; Ddag : EF=+1
template<int EF>
__device__ __forceinline__ void dirac(const float2* __restrict__ U,
                                      const float2* __restrict__ vin,
                                      float2* __restrict__ vout, int t)
{
  if (t < NV) {
    const int s = t & 1, site = t >> 1;
    const int yi = site & 7, xi = site >> 3;
    const int xp = (xi+1)&7, xm = (xi-1)&7, yp = (yi+1)&7, ym = (yi-1)&7;
    float2 acc;
    {
      const int bf = (xp<<4) + (yi<<1);
      float2 fs = vin[bf + s], fo = vin[bf + (s^1)];
      float2 cf = (EF > 0) ? cadd(fs, fo) : csub(fs, fo);
      acc = cmul(U[(xi<<3)+yi], cf);
      const int bb = (xm<<4) + (yi<<1);
      float2 bs = vin[bb + s], bo = vin[bb + (s^1)];
      float2 cb = (EF > 0) ? csub(bs, bo) : cadd(bs, bo);
      acc = cadd(acc, cmulc(U[(xm<<3)+yi], cb));
    }
    {
      const float tg = s ? 1.0f : -1.0f;
      const float gf = (float)EF * tg;
      const int bf = (xi<<4) + (yp<<1);
      float2 fs = vin[bf + s], fo = vin[bf + (s^1)];
      float2 cf = make_float2(fmaf(-gf, fo.y, fs.x), fmaf(gf, fo.x, fs.y));
      acc = cadd(acc, cmul(U[64 + (xi<<3)+yi], cf));
      const float gb = -gf;
      const int bb = (xi<<4) + (ym<<1);
      float2 bs = vin[bb + s], bo = vin[bb + (s^1)];
      float2 cb = make_float2(fmaf(-gb, bo.y, bs.x), fmaf(gb, bo.x, bs.y));
      acc = cadd(acc, cmulc(U[64 + (xi<<3)+ym], cb));
    }
    float2 v0 = vin[t];
    vout[t] = make_float2(fmaf(-KAP, acc.x, v0.x), fmaf(-KAP, acc.y, v0.y));
  }
  __syncthreads();
}

// z = L^H (L v), L in skewed, granule-XOR-swizzled, zero-filled LDS triangle.
// Pair-balanced schedule (uniform 8-iter loop + half-wave epilogue).
// L reads in pass 1 are physically contiguous (swizzle folded into the v index);
// pass 2 column reads get key = c<<1 per lane -> 4 distinct bank-pairs (conflict-free).
__device__ __forceinline__ void precond(const float2* __restrict__ Lc2,
                                        const float2* __restrict__ vin,
                                        float2* __restrict__ wvv,
                                        float2* __restrict__ vout,
                                        int w, int lane)
{
  const int c  = lane & 3;
  const int g  = lane >> 2;
  const int q  = g & 7;
  const int h  = g >> 3;
  const int c2 = c << 1;
  const int rlo = (w << 3) + q;        // 0..63
  const int rhi = 127 - rlo;           // 64..127
  const int bLo = soff8(rlo);
  const int bHi = soff8(rhi);
  const int keyLo = skey(rlo);
  const int keyHi = skey(rhi);

  // ---- pass 1: w_r = sum_{j<=r} L[r][j] v[j] ----
  {
    float2 a0 = f2(0.f, 0.f), a1 = f2(0.f, 0.f);
    #pragma unroll
    for (int i = 0; i < 8; ++i) {
      if (i <= w) {
        // A: rlo slab i ; B: rhi slab 8-w+i
        const int k    = h ? (8 - w + i) : i;
        const int base = h ? bHi : bLo;
        const int keyR = h ? keyHi : keyLo;
        const float4 Lp = *(const float4*)&Lc2[base + (k << 3) + c2];
        const float4 vp = *(const float4*)&vin[(k << 3) + (c2 ^ keyR)];
        a0 = cmac(cmac(a0, f2(Lp.x,Lp.y), f2(vp.x,vp.y)), f2(Lp.z,Lp.w), f2(vp.z,vp.w));
      } else {
        // A: rhi slab i-w-1 ; B: rhi slab 8-w+i
        const int k  = h ? (8 - w + i) : (i - w - 1);
        const float4 Lp = *(const float4*)&Lc2[bHi + (k << 3) + c2];
        const float4 vp = *(const float4*)&vin[(k << 3) + (c2 ^ keyHi)];
        a1 = cmac(cmac(a1, f2(Lp.x,Lp.y), f2(vp.x,vp.y)), f2(Lp.z,Lp.w), f2(vp.z,vp.w));
      }
    }
    if (!h) {  // epilogue slab 9 of group A: rhi slab 7-w
      const int k = 7 - w;
      const float4 Lp = *(const float4*)&Lc2[bHi + (k << 3) + c2];
      const float4 vp = *(const float4*)&vin[(k << 3) + (c2 ^ keyHi)];
      a1 = cmac(cmac(a1, f2(Lp.x,Lp.y), f2(vp.x,vp.y)), f2(Lp.z,Lp.w), f2(vp.z,vp.w));
    }
    // h=0: a0 = full rlo, a1 = rhi part ; h=1: a0+a1 = rhi part
    float2 vLo = h ? f2(0.f, 0.f) : a0;
    float2 vHi = h ? cadd(a0, a1) : a1;
    vLo = red8(vLo);
    vHi = red8(vHi);
    if (c == 0) wvv[h ? rhi : rlo] = h ? vHi : vLo;
  }
  __syncthreads();

  // ---- pass 2: z_j = sum_{i>=j} conj(L[i][j]) w[i] ----
  {
    const int key2 = c2;                // skey(8k+c2) == skey(8k+c2+1) == c<<1 for all k
    float2 a0 = f2(0.f, 0.f), a1 = f2(0.f, 0.f);
    #pragma unroll
    for (int i = 0; i < 8; ++i) {
      int k, j;
      if (i <= w) {
        // A: jhi slab 15-w+i ; B: jlo slab 8+i
        k = h ? (8 + i) : (15 - w + i);
        j = h ? rlo : rhi;
      } else {
        // A: jlo slab i-1 ; B: jlo slab 8+i
        k = h ? (8 + i) : (i - 1);
        j = rlo;
      }
      const int u    = (k + 1) << 3;                 // padded row length of row 8k+*
      // soff8(8k+c2) = u*(4k+c2) + 16k + 2*c2 ; read col j at phys (j ^ key2)
      const int off0 = u * ((k << 2) + c2) + (k << 4) + (c2 << 1) + (j ^ key2);
      const int off1 = off0 + u + 2;                 // next row: +len8 +skew
      const int i0   = (k << 3) + c2;
      const float2 La = Lc2[off0];
      const float2 Lb = Lc2[off1];
      const float4 wp = *(const float4*)&wvv[i0];
      if (i <= w) a0 = cmacc(cmacc(a0, La, f2(wp.x,wp.y)), Lb, f2(wp.z,wp.w));
      else        a1 = cmacc(cmacc(a1, La, f2(wp.x,wp.y)), Lb, f2(wp.z,wp.w));
    }
    if (!h) {  // epilogue slab 9 of group A: jlo slab 7 (rows 56+c2, 57+c2)
      const int o0 = (64 * (28 + c2)) + 112 + (c2 << 1) + (rlo ^ key2);
      const float2 La = Lc2[o0];
      const float2 Lb = Lc2[o0 + 66];               // +len8(64) +skew(2)
      const float4 wp = *(const float4*)&wvv[56 + c2];
      a1 = cmacc(cmacc(a1, La, f2(wp.x,wp.y)), Lb, f2(wp.z,wp.w));
    }
    // h=0: a0 = full jhi, a1 = jlo part ; h=1: a0+a1 = jlo part
    float2 vJhi = h ? f2(0.f, 0.f) : a0;
    float2 vJlo = h ? cadd(a0, a1) : a1;
    vJhi = red8(vJhi);
    vJlo = red8(vJlo);
    if (c == 0) vout[h ? rlo : rhi] = h ? vJlo : vJhi;
  }
  __syncthreads();                                   // z visible to all consumers
}

// conj(a).c over t<128; scal slot double-buffered; internal barrier.
__device__ __forceinline__ float2 block_dot(const float2* __restrict__ a, const float2* __restrict__ c,
                            float2* __restrict__ scal, int t, int slot)
{
  if (t < NV) {
    float2 v = cmacc(f2(0.f,0.f), a[t], c[t]);
    #pragma unroll
    for (int off = 32; off > 0; off >>= 1) {
      v.x += __shfl_down(v.x, off, 64);
      v.y += __shfl_down(v.y, off, 64);
    }
    if ((t & 63) == 0) scal[(slot<<1) + (t >> 6)] = v;
  }
  __syncthreads();
  return cadd(scal[slot<<1], scal[(slot<<1)+1]);
}

extern "C" __global__ void __launch_bounds__(TPB, 4)
cg_loss_kernel(const float* __restrict__ nre, const float* __restrict__ nim,
               const float* __restrict__ theta, const float* __restrict__ bin,
               float* __restrict__ out, float invB)
{
  __shared__ __align__(16) float2 Lc2[NPAD8R];      // 71680 B skewed+swizzled triangle
  __shared__ __align__(16) float2 Uc[128];
  __shared__ __align__(16) float2 bv[NV], xv[NV], rv[NV], pv[NV];
  __shared__ __align__(16) float2 zv[NV], Apv[NV], tv[NV], wv[NV];
  __shared__ float2 scal[8];
  // total LDS = 71680 + 1024 + 8192 + 64 = 80960 B -> 2 blocks/CU

  const int t = threadIdx.x;
  const long long b = blockIdx.x;
  const int w = t >> 6, lane = t & 63;

  // ---- zero the padded triangle (pads/gaps must read as 0), init vectors ----
  for (int p = t; p < NPAD8R; p += TPB) Lc2[p] = make_float2(0.f, 0.f);
  if (t < NV) {
    float th = theta[b * 128 + t];
    float sn, cs;
    sincosf(th, &sn, &cs);
    Uc[t] = make_float2(cs, sn);                    // exp(i*theta)
    float bb = bin[b * 128 + t];
    bv[t] = make_float2(bb, 0.f);
    xv[t] = make_float2(0.f, 0.f);
    rv[t] = make_float2(bb, 0.f);                   // r = b - A(0)
  }
  __syncthreads();

  // ---- stage L into skewed+swizzled LDS; global reads fully coalesced ----
  {
    const float* nreb = nre + b * NTRI;
    const float* nimb = nim + b * NTRI;
    for (int p = t; p < NTRI; p += TPB) {
      float re = nreb[p], im = nimb[p];
      int r = (int)((sqrtf(8.f * (float)p + 1.f) - 1.f) * 0.5f + 1e-3f);
      int tr = (r * (r + 1)) >> 1;
      if (tr > p)               { tr -= r; --r; }        // tri(r-1) = tri(r) - r
      else if (tr + r + 1 <= p) { tr += r + 1; ++r; }
      Lc2[soff8(r) + ((p - tr) ^ skey(r))] = make_float2(re, im);
    }
  }
  __syncthreads();

  precond(Lc2, rv, wv, zv, w, lane);                // z = M r
  if (t < NV) pv[t] = zv[t];
  float2 rz = block_dot(rv, zv, scal, t, 0);        // internal barrier publishes pv

  #pragma unroll 1
  for (int it = 0; it < MAXIT; ++it) {
    dirac<-1>(Uc, pv, tv, t);                       // t1 = D p
    dirac<+1>(Uc, tv, Apv, t);                      // Ap = Ddag t1
    float2 pAp = block_dot(pv, Apv, scal, t, 1);
    if (t < NV) {
      float2 alpha = cdiv(rz, pAp);
      xv[t] = cmac(xv[t], alpha, pv[t]);            // x += alpha p
      rv[t] = csub(rv[t], cmul(alpha, Apv[t]));     // r -= alpha Ap
    }
    __syncthreads();                                // rv visible to pass 1
    precond(Lc2, rv, wv, zv, w, lane);              // z = M r
    float2 rz2 = block_dot(rv, zv, scal, t, 0);
    if (t < NV) {
      float2 beta = cdiv(rz2, rz);
      pv[t] = cmac(zv[t], beta, pv[t]);             // p = z + beta p
    }
    rz = rz2;
    __syncthreads();                                // pv visible to next dirac
  }

  // res = A x - b ; rn = ||res||
  dirac<-1>(Uc, xv, tv, t);
  dirac<+1>(Uc, tv, Apv, t);
  if (t < NV) {
    float2 d = csub(Apv[t], bv[t]);
    float v = fmaf(d.x, d.x, d.y * d.y);
    #pragma unroll
    for (int off = 32; off > 0; off >>= 1) v += __shfl_down(v, off, 64);
    if ((t & 63) == 0) scal[4 + (t >> 6)].x = v;
  }
  __syncthreads();
  if (t == 0) {
    float rn = sqrtf(scal[4].x + scal[5].x);
    atomicAdd(out, rn * invB);
  }
}

extern "C" void kernel_launch(void* const* d_in, const int* in_sizes, int n_in,
                              void* d_out, int out_size, void* d_ws, size_t ws_size,
                              hipStream_t stream)
{
  const float* nre   = (const float*)d_in[0];
  const float* nim   = (const float*)d_in[1];
  const float* theta = (const float*)d_in[2];
  const float* bin   = (const float*)d_in[3];
  float* out = (float*)d_out;
  const int B = in_sizes[0] / NTRI;   // 2048

  hipMemsetAsync(out, 0, sizeof(float), stream);
  cg_loss_kernel<<<B, TPB, 0, stream>>>(nre, nim, theta, bin, out, 1.0f / (float)B);
}